// Round 15
// baseline (127.068 us; speedup 1.0000x reference)
//
#include <hip/hip_runtime.h>
#include <hip/hip_bf16.h>

#define NUM_RATINGS 10
#define WIN 1024
#define MAXT 74   // max padded tiles/window: 1024/16 + 10 pad-tails

typedef short bf16x8 __attribute__((ext_vector_type(8)));
typedef float f32x4 __attribute__((ext_vector_type(4)));

// ---- RNE f32 -> bf16 packing (static indexing only) ----
static __device__ __forceinline__ bf16x8 rne8(float4 a, float4 b) {
    float f[8] = {a.x, a.y, a.z, a.w, b.x, b.y, b.z, b.w};
    union { unsigned short us[8]; bf16x8 v; } U;
    #pragma unroll
    for (int i = 0; i < 8; ++i) {
        unsigned u = __float_as_uint(f[i]);
        U.us[i] = (unsigned short)((u + 0x7fffu + ((u >> 16) & 1u)) >> 16);
    }
    return U.v;
}

static __device__ __forceinline__ bf16x8 rne8s(float4 a, float4 b, float s) {
    float f[8] = {a.x, a.y, a.z, a.w, b.x, b.y, b.z, b.w};
    union { unsigned short us[8]; bf16x8 v; } U;
    #pragma unroll
    for (int i = 0; i < 8; ++i) {
        unsigned u = __float_as_uint(f[i] * s);
        U.us[i] = (unsigned short)((u + 0x7fffu + ((u >> 16) & 1u)) >> 16);
    }
    return U.v;
}

// ---------------- W -> bf16 B-fragment precompute (verified round 6) -------
// wf[(r*8 + j)*64 + lane], j = tt*2 + ks.
// Lane l (eh=l&15, kg=l>>4) holds W[r][16*tt + eh][32*ks + 8*kg + i], i=0..7.
__global__ void k_wfrag(const float* __restrict__ w, bf16x8* __restrict__ wf) {
    int r = blockIdx.x;
    int lane = threadIdx.x & 63;
    int eh = lane & 15, kg = lane >> 4;
    #pragma unroll
    for (int j = 0; j < 8; ++j) {
        int tt = j >> 1, ks = j & 1;
        const float4* p = reinterpret_cast<const float4*>(
            w + ((size_t)r << 12) + (size_t)(16 * tt + eh) * 64 + 32 * ks + 8 * kg);
        wf[(r * 8 + j) * 64 + lane] = rne8(p[0], p[1]);
    }
}

#define LOADB(rr) { \
    _Pragma("unroll") \
    for (int j_ = 0; j_ < 8; ++j_) B[j_] = wf[((rr) * 8 + j_) * 64 + lane]; }

// x slot XS loaded from meta slot m##MS
#define XLOAD(XS, MS) { \
    const float4* xq_ = reinterpret_cast<const float4*>( \
        embed + ((size_t)(m##MS.x < 0 ? 0 : m##MS.x) << 6)); \
    x##XS##0 = xq_[2 * kg];     x##XS##1 = xq_[2 * kg + 1]; \
    x##XS##2 = xq_[8 + 2 * kg]; x##XS##3 = xq_[9 + 2 * kg]; }

// compute tile TC from slots (MS, XS); then re-issue slot for tile TC+4
#define STEP(TC, MS, XS) { \
    int tc_ = (TC); \
    if (tc_ < t1) { \
        int tslot_ = tc_ << 4; \
        int r_ = 0; \
        r_ += tslot_ >= pf1; r_ += tslot_ >= pf2; r_ += tslot_ >= pf3; \
        r_ += tslot_ >= pf4; r_ += tslot_ >= pf5; r_ += tslot_ >= pf6; \
        r_ += tslot_ >= pf7; r_ += tslot_ >= pf8; r_ += tslot_ >= pf9; \
        if (r_ != cur_r) { cur_r = r_; LOADB(r_) } \
        float s_ = m##MS.x < 0 ? 0.f : __int_as_float(m##MS.y); \
        bf16x8 a0_ = rne8s(x##XS##0, x##XS##1, s_); \
        bf16x8 a1_ = rne8s(x##XS##2, x##XS##3, s_); \
        f32x4 acc[4]; \
        _Pragma("unroll") \
        for (int tt_ = 0; tt_ < 4; ++tt_) acc[tt_] = (f32x4){0.f, 0.f, 0.f, 0.f}; \
        _Pragma("unroll") \
        for (int tt_ = 0; tt_ < 4; ++tt_) { \
            acc[tt_] = __builtin_amdgcn_mfma_f32_16x16x32_bf16(a0_, B[2 * tt_],     acc[tt_], 0, 0, 0); \
            acc[tt_] = __builtin_amdgcn_mfma_f32_16x16x32_bf16(a1_, B[2 * tt_ + 1], acc[tt_], 0, 0, 0); \
        } \
        int vnd_ = m##MS.x; \
        int kg4_ = kg << 2; \
        _Pragma("unroll") \
        for (int rg_ = 0; rg_ < 4; ++rg_) { \
            int nd2_ = __shfl(vnd_, kg4_ + rg_, 64); \
            if (nd2_ >= 0) { \
                float* po_ = out + ((size_t)nd2_ << 6) + eh; \
                __builtin_nontemporal_store(acc[0][rg_], po_); \
                __builtin_nontemporal_store(acc[1][rg_], po_ + 16); \
                __builtin_nontemporal_store(acc[2][rg_], po_ + 32); \
                __builtin_nontemporal_store(acc[3][rg_], po_ + 48); \
            } \
        } \
        int tp_ = tc_ + 4; if (tp_ > t1 - 1) tp_ = t1 - 1; \
        m##MS = smeta[(tp_ << 4) + eh]; \
        XLOAD(XS, MS) \
    } }

// ---------------- windowed local-sort main ----------------
// One block = one 1024-edge window. Phase 1: LDS counting sort by rating
// (padded buckets, pads nd=-1). Phase 2: 4 waves over contiguous tile
// ranges with a 4-DEEP meta/x register pipeline (named slots, unroll-4) —
// each tile's window-local x-gather has ~4 tiles of compute slack.
// D layout (m89, verified r4-r14): row(edge) = 4*kg + rg, col(out) = 16*tt+eh.
__global__ __launch_bounds__(256) void k_main(
    const float* __restrict__ embed, const bf16x8* __restrict__ wf,
    const float* __restrict__ invc, const int* __restrict__ enode,
    const int* __restrict__ erating, float* __restrict__ out, int E) {

    __shared__ int2 smeta[MAXT * 16];          // 9472 B
    __shared__ int shist[NUM_RATINGS];
    __shared__ int spoff[NUM_RATINGS + 1];

    int tid = threadIdx.x;
    int base = blockIdx.x * WIN;

    if (tid < NUM_RATINGS) shist[tid] = 0;
    for (int i = tid; i < MAXT * 16; i += 256) smeta[i] = make_int2(-1, 0);
    __syncthreads();

    int er[4], rr[4], kk[4];
    #pragma unroll
    for (int i = 0; i < 4; ++i) {
        int e = base + i * 256 + tid;
        er[i] = e;
        if (e < E) {
            rr[i] = erating[e];
            kk[i] = atomicAdd(&shist[rr[i]], 1);
        }
    }
    __syncthreads();
    if (tid == 0) {
        int s = 0;
        #pragma unroll
        for (int r = 0; r < NUM_RATINGS; ++r) { spoff[r] = s; s += (shist[r] + 15) & ~15; }
        spoff[NUM_RATINGS] = s;
    }
    __syncthreads();
    #pragma unroll
    for (int i = 0; i < 4; ++i)
        if (er[i] < E)
            smeta[spoff[rr[i]] + kk[i]] =
                make_int2(enode[er[i]], __float_as_int(invc[er[i]]));
    __syncthreads();

    int pf1 = spoff[1], pf2 = spoff[2], pf3 = spoff[3], pf4 = spoff[4];
    int pf5 = spoff[5], pf6 = spoff[6], pf7 = spoff[7], pf8 = spoff[8];
    int pf9 = spoff[9];
    int Tp = spoff[NUM_RATINGS] >> 4;

    int lane = tid & 63, wv = tid >> 6;
    int eh = lane & 15, kg = lane >> 4;

    int tpw = (Tp + 3) >> 2;
    int t0 = wv * tpw;
    int t1 = t0 + tpw; if (t1 > Tp) t1 = Tp;
    if (t0 >= t1) return;   // no barriers after this point
    int tL = t1 - 1;

    // 4-deep pipeline prologue: meta + x for tiles t0..t0+3 (clamped)
    int q1 = t0 + 1 > tL ? tL : t0 + 1;
    int q2 = t0 + 2 > tL ? tL : t0 + 2;
    int q3 = t0 + 3 > tL ? tL : t0 + 3;
    int2 m0 = smeta[(t0 << 4) + eh];
    int2 m1 = smeta[(q1 << 4) + eh];
    int2 m2 = smeta[(q2 << 4) + eh];
    int2 m3 = smeta[(q3 << 4) + eh];

    float4 xA0, xA1, xA2, xA3, xB0, xB1, xB2, xB3;
    float4 xC0, xC1, xC2, xC3, xD0, xD1, xD2, xD3;
    XLOAD(A, 0)
    XLOAD(B, 1)
    XLOAD(C, 2)
    XLOAD(D, 3)

    int cur_r = -1;
    bf16x8 B[8];

    for (int t = t0; t < t1; t += 4) {
        STEP(t + 0, 0, A)
        STEP(t + 1, 1, B)
        STEP(t + 2, 2, C)
        STEP(t + 3, 3, D)
    }
}

extern "C" void kernel_launch(void* const* d_in, const int* in_sizes, int n_in,
                              void* d_out, int out_size, void* d_ws, size_t ws_size,
                              hipStream_t stream) {
    const float* embed   = (const float*)d_in[0];
    const float* weights = (const float*)d_in[1];
    const float* invc    = (const float*)d_in[2];
    const int*   enode   = (const int*)d_in[3];
    const int*   erating = (const int*)d_in[4];
    float* out = (float*)d_out;

    int E = in_sizes[3];

    bf16x8* wf = (bf16x8*)d_ws;   // 80 KiB W fragments (L2-hot)

    hipLaunchKernelGGL(k_wfrag, dim3(NUM_RATINGS), dim3(64), 0, stream, weights, wf);

    int nW = (E + WIN - 1) / WIN;
    hipLaunchKernelGGL(k_main, dim3(nW), dim3(256), 0, stream,
                       embed, wf, invc, enode, erating, out, E);
}